// Round 5
// baseline (884.514 us; speedup 1.0000x reference)
//
#include <hip/hip_runtime.h>
#include <stdint.h>

typedef unsigned short u16;
typedef unsigned int u32;
typedef __attribute__((ext_vector_type(8))) short s16x8;   // 8 bf16 (4 VGPRs) MFMA frag
typedef __attribute__((ext_vector_type(4))) float f32x4;   // MFMA accum / vec4

// ---------- bf16 helpers ----------
__device__ __forceinline__ u16 f2bf(float f) {
  union { float f; u32 u; } v; v.f = f;
  u32 u = v.u;
  return (u16)((u + 0x7fffu + ((u >> 16) & 1u)) >> 16);
}
__device__ __forceinline__ u32 pk2bf(float a, float b) {
  return (u32)f2bf(a) | ((u32)f2bf(b) << 16);
}

// ---------- constants ----------
#define NT 49        // tokens per window
#define CD 256       // dim
#define NWIN 4096    // 64 imgs * 64 windows
#define SX_RS 264    // x / attn-out bf16 row stride

// workspace offsets (bytes)
#define WS_BIASC 8192                 // 4*8*64*64 f32 = 524288
#define WS_WQKV  (8192 + 524288)      // 532480: 384 KB
#define WS_WPROJ (532480 + 393216)    // 925696: 128 KB

// =====================================================================
// Kernel A: CPB MLP, parallel over j: 169 blocks x 256 threads
// =====================================================================
__global__ void cpb_table_kernel(const float* __restrict__ coords,
                                 const float* __restrict__ w1,
                                 const float* __restrict__ b1,
                                 const float* __restrict__ w2,
                                 float* __restrict__ table) {
  __shared__ float red[4][8];
  const int p = blockIdx.x;
  const int tid = threadIdx.x;
  const float c0 = coords[p * 2], c1 = coords[p * 2 + 1];
  float acc[8];
#pragma unroll
  for (int h = 0; h < 8; ++h) acc[h] = 0.f;
  for (int j = tid; j < 512; j += 256) {
    float hid = fmaxf(fmaf(c0, w1[j * 2], fmaf(c1, w1[j * 2 + 1], b1[j])), 0.f);
#pragma unroll
    for (int h = 0; h < 8; ++h) acc[h] = fmaf(hid, w2[h * 512 + j], acc[h]);
  }
#pragma unroll
  for (int h = 0; h < 8; ++h) {
    float v = acc[h];
    v += __shfl_xor(v, 1, 64);  v += __shfl_xor(v, 2, 64);
    v += __shfl_xor(v, 4, 64);  v += __shfl_xor(v, 8, 64);
    v += __shfl_xor(v, 16, 64); v += __shfl_xor(v, 32, 64);
    if ((tid & 63) == 0) red[tid >> 6][h] = v;
  }
  __syncthreads();
  if (tid < 8)
    table[p * 8 + tid] = red[0][tid] + red[1][tid] + red[2][tid] + red[3][tid];
}

// =====================================================================
// Kernel B: combined bias table, 4 mask types; pads -> -1e9
// =====================================================================
__global__ void biasc_prep(const float* __restrict__ table,
                           const int* __restrict__ rpi,
                           const float* __restrict__ mask,
                           float* __restrict__ biasC) {
  int idx = blockIdx.x * 256 + threadIdx.x;
  if (idx >= 4 * 8 * 4096) return;
  int t = idx >> 15;
  int h = (idx >> 12) & 7;
  int q = (idx >> 6) & 63;
  int kv = idx & 63;
  float v = -1e9f;
  if (q < 49 && kv < 49) {
    float tb = table[rpi[q * 49 + kv] * 8 + h];
    float rpb = 16.f / (1.f + __expf(-tb));
    int wimg = ((t & 2) ? 56 : 0) + ((t & 1) ? 7 : 0);
    v = rpb + mask[wimg * 2401 + q * 49 + kv];
  }
  biasC[idx] = v;
}

// =====================================================================
// Kernel C: weights f32 -> bf16, MFMA fragment order.
// frag[ntile][kk][lane][8]; value = W[nt*16+(l&15)][kk*32+(l>>4)*8+j]
// =====================================================================
__global__ void wcvt_kernel(const float* __restrict__ qkv_w,
                            const float* __restrict__ proj_w,
                            u16* __restrict__ wq, u16* __restrict__ wp) {
  int t = blockIdx.x * 256 + threadIdx.x;
  if (t >= 32768) return;
  const float* src; u16* dst; int idx;
  if (t < 24576) { idx = t; src = qkv_w; dst = wq + (size_t)idx * 8; }
  else           { idx = t - 24576; src = proj_w; dst = wp + (size_t)idx * 8; }
  int nt = idx >> 9, rem = idx & 511;
  int kk = rem >> 6, l = rem & 63;
  int n = nt * 16 + (l & 15);
  int k = kk * 32 + (l >> 4) * 8;
  const float4* s = (const float4*)(src + (size_t)n * 256 + k);
  float4 v0 = s[0], v1 = s[1];
  *(uint4*)dst = make_uint4(pk2bf(v0.x, v0.y), pk2bf(v0.z, v0.w),
                            pk2bf(v1.x, v1.y), pk2bf(v1.z, v1.w));
}

// gather one s16x8 frag from packed bf16 pairs on 2 source lanes with a
// lo/hi register select (uniform register operands, per-lane select).
__device__ __forceinline__ s16x8 gather4(const u32 lo0, const u32 lo1,
                                         const u32 hi0, const u32 hi1,
                                         int srcL, int srcH, bool hi) {
  union { u32 u[4]; s16x8 v; } r;
  u32 a0 = (u32)__shfl((int)lo0, srcL, 64), b0 = (u32)__shfl((int)hi0, srcL, 64);
  u32 a1 = (u32)__shfl((int)lo1, srcL, 64), b1 = (u32)__shfl((int)hi1, srcL, 64);
  u32 a2 = (u32)__shfl((int)lo0, srcH, 64), b2 = (u32)__shfl((int)hi0, srcH, 64);
  u32 a3 = (u32)__shfl((int)lo1, srcH, 64), b3 = (u32)__shfl((int)hi1, srcH, 64);
  r.u[0] = hi ? b0 : a0; r.u[1] = hi ? b1 : a1;
  r.u[2] = hi ? b2 : a2; r.u[3] = hi ? b3 : a3;
  return r.v;
}

// =====================================================================
// Fused per-window kernel: 4096 blocks x 512 threads = 8 waves.
// Wave h owns head h end-to-end: computes q_h,k_h,v_h (register-resident),
// norms in regs, S^T/softmax/PV in regs. Only x/attn-out use LDS (33 KB)
// -> 2 blocks/CU. 3 barriers per window.
// =====================================================================
__global__ __launch_bounds__(512, 4) void swin_fused(
    const float* __restrict__ x,
    const float* __restrict__ q_bias, const float* __restrict__ v_bias,
    const float* __restrict__ logit_scale, const float* __restrict__ biasC,
    const u16* __restrict__ wq, const u16* __restrict__ wp,
    const float* __restrict__ proj_b,
    float* __restrict__ out) {
  __shared__ __attribute__((aligned(16))) u16 sX[64 * SX_RS];  // 33792 B

  const int tid = threadIdx.x;
  const int wid = blockIdx.x;
  const int wimg = wid & 63;
  const int hh = tid >> 6;   // wave / head
  const int il = tid & 63;   // lane
  const int lr = il & 15;
  const int lg = il >> 4;
  const int srcL = lr + 32 * (lg & 1);   // shared by all frag re-layouts
  const int srcH = srcL + 16;
  const bool hi = (il & 32) != 0;

  // ---- P1: x loads first; zero pad rows; convert to bf16 LDS ----
  float4 xr[6]; float4 xr6;
  {
    const float4* xg = (const float4*)(x + (size_t)wid * (NT * CD));
#pragma unroll
    for (int i = 0; i < 6; ++i) xr[i] = xg[tid + 512 * i];
    if (tid < 64) xr6 = xg[3072 + tid];
  }
  const float scl = __expf(fminf(logit_scale[hh], 4.605170186f));
  {
    u32* zx = (u32*)&sX[49 * SX_RS];     // rows 49..63: stay zero forever
    for (int e = tid; e < 1980; e += 512) zx[e] = 0;
  }
  {
#pragma unroll
    for (int i = 0; i < 6; ++i) {
      const int e = tid + 512 * i;
      const int row = e >> 6, c4 = e & 63;
      float4 v = xr[i];
      *(uint2*)&sX[row * SX_RS + c4 * 4] = make_uint2(pk2bf(v.x, v.y), pk2bf(v.z, v.w));
    }
    if (tid < 64) {
      const int e = 3072 + tid;
      const int row = e >> 6, c4 = e & 63;
      float4 v = xr6;
      *(uint2*)&sX[row * SX_RS + c4 * 4] = make_uint2(pk2bf(v.x, v.y), pk2bf(v.z, v.w));
    }
  }
  __syncthreads();

  // ---- P2 pass 1: q,k for head hh (swapped mfma: lane token=16mt+lr) ----
  const u16* wqbase = wq + il * 8;
  s16x8 qbf[4], kaf[4];
  {
    f32x4 aq[2][4], ak[2][4];
#pragma unroll
    for (int n2 = 0; n2 < 2; ++n2)
#pragma unroll
      for (int mt = 0; mt < 4; ++mt) {
        aq[n2][mt] = (f32x4){0.f, 0.f, 0.f, 0.f};
        ak[n2][mt] = (f32x4){0.f, 0.f, 0.f, 0.f};
      }
    const int nq0 = 2 * hh, nk0 = 16 + 2 * hh;
#pragma unroll
    for (int kk = 0; kk < 8; ++kk) {
      s16x8 a[4];
#pragma unroll
      for (int mt = 0; mt < 4; ++mt)
        a[mt] = *(const s16x8*)&sX[(mt * 16 + lr) * SX_RS + kk * 32 + lg * 8];
      s16x8 bq0 = *(const s16x8*)&wqbase[((nq0 + 0) * 8 + kk) * 512];
      s16x8 bq1 = *(const s16x8*)&wqbase[((nq0 + 1) * 8 + kk) * 512];
      s16x8 bk0 = *(const s16x8*)&wqbase[((nk0 + 0) * 8 + kk) * 512];
      s16x8 bk1 = *(const s16x8*)&wqbase[((nk0 + 1) * 8 + kk) * 512];
#pragma unroll
      for (int mt = 0; mt < 4; ++mt) {
        aq[0][mt] = __builtin_amdgcn_mfma_f32_16x16x32_bf16(bq0, a[mt], aq[0][mt], 0, 0, 0);
        aq[1][mt] = __builtin_amdgcn_mfma_f32_16x16x32_bf16(bq1, a[mt], aq[1][mt], 0, 0, 0);
        ak[0][mt] = __builtin_amdgcn_mfma_f32_16x16x32_bf16(bk0, a[mt], ak[0][mt], 0, 0, 0);
        ak[1][mt] = __builtin_amdgcn_mfma_f32_16x16x32_bf16(bk1, a[mt], ak[1][mt], 0, 0, 0);
      }
    }
    // bias (q only), norms in regs (reduce over lg lanes: same token)
    const float4 qb40 = *(const float4*)(q_bias + 32 * hh + 4 * lg);
    const float4 qb41 = *(const float4*)(q_bias + 32 * hh + 16 + 4 * lg);
    float rq[4], rk[4];
#pragma unroll
    for (int mt = 0; mt < 4; ++mt) {
      aq[0][mt][0] += qb40.x; aq[0][mt][1] += qb40.y;
      aq[0][mt][2] += qb40.z; aq[0][mt][3] += qb40.w;
      aq[1][mt][0] += qb41.x; aq[1][mt][1] += qb41.y;
      aq[1][mt][2] += qb41.z; aq[1][mt][3] += qb41.w;
      float sq = 1e-6f, sk = 1e-6f;
#pragma unroll
      for (int i = 0; i < 4; ++i) {
        sq = fmaf(aq[0][mt][i], aq[0][mt][i], sq);
        sq = fmaf(aq[1][mt][i], aq[1][mt][i], sq);
        sk = fmaf(ak[0][mt][i], ak[0][mt][i], sk);
        sk = fmaf(ak[1][mt][i], ak[1][mt][i], sk);
      }
      sq += __shfl_xor(sq, 16, 64); sq += __shfl_xor(sq, 32, 64);
      sk += __shfl_xor(sk, 16, 64); sk += __shfl_xor(sk, 32, 64);
      rq[mt] = rsqrtf(sq) * scl;
      rk[mt] = rsqrtf(sk);
    }
    // scale, pack pairs, gather into S^T operand frags
    u32 pq[2][4][2], pk_[2][4][2];
#pragma unroll
    for (int n2 = 0; n2 < 2; ++n2)
#pragma unroll
      for (int mt = 0; mt < 4; ++mt) {
        pq[n2][mt][0] = pk2bf(aq[n2][mt][0] * rq[mt], aq[n2][mt][1] * rq[mt]);
        pq[n2][mt][1] = pk2bf(aq[n2][mt][2] * rq[mt], aq[n2][mt][3] * rq[mt]);
        pk_[n2][mt][0] = pk2bf(ak[n2][mt][0] * rk[mt], ak[n2][mt][1] * rk[mt]);
        pk_[n2][mt][1] = pk2bf(ak[n2][mt][2] * rk[mt], ak[n2][mt][3] * rk[mt]);
      }
#pragma unroll
    for (int nt = 0; nt < 4; ++nt) {
      qbf[nt] = gather4(pq[0][nt][0], pq[0][nt][1], pq[1][nt][0], pq[1][nt][1], srcL, srcH, hi);
      kaf[nt] = gather4(pk_[0][nt][0], pk_[0][nt][1], pk_[1][nt][0], pk_[1][nt][1], srcL, srcH, hi);
    }
  }

  // ---- P2 pass 2: v (unswapped: lane d=16n2+lr, tokens 16mt+4lg+i) ----
  s16x8 vbf[2][2];
  {
    f32x4 av[2][4];
#pragma unroll
    for (int n2 = 0; n2 < 2; ++n2)
#pragma unroll
      for (int mt = 0; mt < 4; ++mt) av[n2][mt] = (f32x4){0.f, 0.f, 0.f, 0.f};
    const int nv0 = 32 + 2 * hh;
#pragma unroll
    for (int kk = 0; kk < 8; ++kk) {
      s16x8 a[4];
#pragma unroll
      for (int mt = 0; mt < 4; ++mt)
        a[mt] = *(const s16x8*)&sX[(mt * 16 + lr) * SX_RS + kk * 32 + lg * 8];
      s16x8 bv0 = *(const s16x8*)&wqbase[((nv0 + 0) * 8 + kk) * 512];
      s16x8 bv1 = *(const s16x8*)&wqbase[((nv0 + 1) * 8 + kk) * 512];
#pragma unroll
      for (int mt = 0; mt < 4; ++mt) {
        av[0][mt] = __builtin_amdgcn_mfma_f32_16x16x32_bf16(a[mt], bv0, av[0][mt], 0, 0, 0);
        av[1][mt] = __builtin_amdgcn_mfma_f32_16x16x32_bf16(a[mt], bv1, av[1][mt], 0, 0, 0);
      }
    }
    __syncthreads();   // bar2: ALL x reads done (O will overwrite sX)
    const float bv0s = v_bias[32 * hh + lr];
    const float bv1s = v_bias[32 * hh + 16 + lr];
    u32 pv[2][4][2];
#pragma unroll
    for (int mt = 0; mt < 4; ++mt) {
      pv[0][mt][0] = pk2bf(av[0][mt][0] + bv0s, av[0][mt][1] + bv0s);
      pv[0][mt][1] = pk2bf(av[0][mt][2] + bv0s, av[0][mt][3] + bv0s);
      pv[1][mt][0] = pk2bf(av[1][mt][0] + bv1s, av[1][mt][1] + bv1s);
      pv[1][mt][1] = pk2bf(av[1][mt][2] + bv1s, av[1][mt][3] + bv1s);
    }
#pragma unroll
    for (int nd = 0; nd < 2; ++nd)
#pragma unroll
      for (int s = 0; s < 2; ++s)
        vbf[nd][s] = gather4(pv[nd][2 * s][0], pv[nd][2 * s][1],
                             pv[nd][2 * s + 1][0], pv[nd][2 * s + 1][1], srcL, srcH, hi);
  }

  // ---- P3: S^T (pre-scaled) + bias -> softmax -> PV -> O to sX ----
  {
    const int type = (((wimg >> 3) == 7) ? 2 : 0) | (((wimg & 7) == 7) ? 1 : 0);
    const float* bp = biasC + ((size_t)(type * 8 + hh) << 12);
    f32x4 sacc[4][4];   // [nt(q)][mt(kv)]
#pragma unroll
    for (int nt = 0; nt < 4; ++nt)
#pragma unroll
      for (int mt = 0; mt < 4; ++mt)
        sacc[nt][mt] = __builtin_amdgcn_mfma_f32_16x16x32_bf16(
            kaf[mt], qbf[nt], (f32x4){0.f, 0.f, 0.f, 0.f}, 0, 0, 0);
    float invv[4];
    u32 pkk[4][4][2];
#pragma unroll
    for (int nt = 0; nt < 4; ++nt) {
      float mx = -3e38f;
#pragma unroll
      for (int mt = 0; mt < 4; ++mt) {
        f32x4 b4 = *(const f32x4*)(bp + (lr + 16 * nt) * 64 + 16 * mt + 4 * lg);
        sacc[nt][mt] += b4;
#pragma unroll
        for (int i = 0; i < 4; ++i) mx = fmaxf(mx, sacc[nt][mt][i]);
      }
      mx = fmaxf(mx, __shfl_xor(mx, 16, 64));
      mx = fmaxf(mx, __shfl_xor(mx, 32, 64));
      float sm = 0.f;
#pragma unroll
      for (int mt = 0; mt < 4; ++mt)
#pragma unroll
        for (int i = 0; i < 4; ++i) {
          float e = __expf(sacc[nt][mt][i] - mx);
          sacc[nt][mt][i] = e;
          sm += e;
        }
      sm += __shfl_xor(sm, 16, 64);
      sm += __shfl_xor(sm, 32, 64);
      invv[nt] = 1.0f / sm;
#pragma unroll
      for (int mt = 0; mt < 4; ++mt) {
        pkk[nt][mt][0] = pk2bf(sacc[nt][mt][0], sacc[nt][mt][1]);
        pkk[nt][mt][1] = pk2bf(sacc[nt][mt][2], sacc[nt][mt][3]);
      }
    }
    // PV: P^T -> A-frag-of-B redistribution (same src lanes), swapped mfma
    f32x4 oacc[4][2];
#pragma unroll
    for (int mo = 0; mo < 4; ++mo)
#pragma unroll
      for (int nd = 0; nd < 2; ++nd) oacc[mo][nd] = (f32x4){0.f, 0.f, 0.f, 0.f};
#pragma unroll
    for (int mo = 0; mo < 4; ++mo) {
#pragma unroll
      for (int s = 0; s < 2; ++s) {
        u32 a0 = (u32)__shfl((int)pkk[mo][2 * s][0],     srcL, 64);
        u32 b0 = (u32)__shfl((int)pkk[mo][2 * s + 1][0], srcL, 64);
        u32 a1 = (u32)__shfl((int)pkk[mo][2 * s][1],     srcL, 64);
        u32 b1 = (u32)__shfl((int)pkk[mo][2 * s + 1][1], srcL, 64);
        u32 a2 = (u32)__shfl((int)pkk[mo][2 * s][0],     srcH, 64);
        u32 b2 = (u32)__shfl((int)pkk[mo][2 * s + 1][0], srcH, 64);
        u32 a3 = (u32)__shfl((int)pkk[mo][2 * s][1],     srcH, 64);
        u32 b3 = (u32)__shfl((int)pkk[mo][2 * s + 1][1], srcH, 64);
        union { u32 u[4]; s16x8 v; } pu;
        pu.u[0] = hi ? b0 : a0;
        pu.u[1] = hi ? b1 : a1;
        pu.u[2] = hi ? b2 : a2;
        pu.u[3] = hi ? b3 : a3;
#pragma unroll
        for (int nd = 0; nd < 2; ++nd)
          oacc[mo][nd] = __builtin_amdgcn_mfma_f32_16x16x32_bf16(
              vbf[nd][s], pu.v, oacc[mo][nd], 0, 0, 0);
      }
    }
    // epilogue: lane q=16mo+lr, d=h*32+16nd+4lg+i -> uint2 stores
#pragma unroll
    for (int mo = 0; mo < 4; ++mo) {
      const int q = 16 * mo + lr;
      if (q < NT) {
        const float invq = invv[mo];
#pragma unroll
        for (int nd = 0; nd < 2; ++nd) {
          uint2 pk;
          pk.x = pk2bf(oacc[mo][nd][0] * invq, oacc[mo][nd][1] * invq);
          pk.y = pk2bf(oacc[mo][nd][2] * invq, oacc[mo][nd][3] * invq);
          *(uint2*)&sX[q * SX_RS + hh * 32 + nd * 16 + 4 * lg] = pk;
        }
      }
    }
  }
  __syncthreads();   // bar3: O complete before P4 reads

  // ---- P4: proj via MFMA (swapped -> float4 global stores) ----
  {
    s16x8 wpr[2][8];
    const u16* wpb = wp + (size_t)hh * 8192 + il * 8;
#pragma unroll
    for (int nt = 0; nt < 2; ++nt)
#pragma unroll
      for (int kk = 0; kk < 8; ++kk)
        wpr[nt][kk] = *(const s16x8*)&wpb[(nt * 8 + kk) * 512];
    float4 pb4[2];
#pragma unroll
    for (int nt = 0; nt < 2; ++nt)
      pb4[nt] = *(const float4*)(proj_b + hh * 32 + nt * 16 + 4 * lg);
    f32x4 acc[2][4];
#pragma unroll
    for (int nt = 0; nt < 2; ++nt)
#pragma unroll
      for (int mt = 0; mt < 4; ++mt) acc[nt][mt] = (f32x4){0.f, 0.f, 0.f, 0.f};
#pragma unroll
    for (int kk = 0; kk < 8; ++kk) {
      s16x8 a[4];
#pragma unroll
      for (int mt = 0; mt < 4; ++mt)
        a[mt] = *(const s16x8*)&sX[(mt * 16 + lr) * SX_RS + kk * 32 + lg * 8];
#pragma unroll
      for (int nt = 0; nt < 2; ++nt)
#pragma unroll
        for (int mt = 0; mt < 4; ++mt)
          acc[nt][mt] = __builtin_amdgcn_mfma_f32_16x16x32_bf16(
              wpr[nt][kk], a[mt], acc[nt][mt], 0, 0, 0);
    }
    float* og = out + (size_t)wid * (NT * CD);
#pragma unroll
    for (int mt = 0; mt < 4; ++mt) {
      const int token = mt * 16 + lr;
      if (token < NT) {
#pragma unroll
        for (int nt = 0; nt < 2; ++nt) {
          float4 st;
          st.x = acc[nt][mt][0] + pb4[nt].x;
          st.y = acc[nt][mt][1] + pb4[nt].y;
          st.z = acc[nt][mt][2] + pb4[nt].z;
          st.w = acc[nt][mt][3] + pb4[nt].w;
          *(float4*)&og[token * CD + hh * 32 + nt * 16 + 4 * lg] = st;
        }
      }
    }
  }
}

extern "C" void kernel_launch(void* const* d_in, const int* in_sizes, int n_in,
                              void* d_out, int out_size, void* d_ws, size_t ws_size,
                              hipStream_t stream) {
  (void)in_sizes; (void)n_in; (void)out_size; (void)ws_size;
  const float* x           = (const float*)d_in[0];
  const float* qkv_w       = (const float*)d_in[1];
  const float* q_bias      = (const float*)d_in[2];
  const float* v_bias      = (const float*)d_in[3];
  const float* logit_scale = (const float*)d_in[4];
  const float* cpb_w1      = (const float*)d_in[5];
  const float* cpb_b1      = (const float*)d_in[6];
  const float* cpb_w2      = (const float*)d_in[7];
  const float* coords      = (const float*)d_in[8];
  const int*   rpi         = (const int*)d_in[9];
  const float* mask        = (const float*)d_in[10];
  const float* proj_w      = (const float*)d_in[11];
  const float* proj_b      = (const float*)d_in[12];
  float* out = (float*)d_out;

  float* table = (float*)d_ws;                        // 169*8 f32
  float* biasC = (float*)((char*)d_ws + WS_BIASC);    // 4*8*4096 f32 (512 KB)
  u16*   wq    = (u16*)((char*)d_ws + WS_WQKV);       // 384 KB bf16
  u16*   wp    = (u16*)((char*)d_ws + WS_WPROJ);      // 128 KB bf16

  hipLaunchKernelGGL(cpb_table_kernel, dim3(169), dim3(256), 0, stream,
                     coords, cpb_w1, cpb_b1, cpb_w2, table);
  hipLaunchKernelGGL(biasc_prep, dim3((4 * 8 * 4096 + 255) / 256), dim3(256),
                     0, stream, table, rpi, mask, biasC);
  hipLaunchKernelGGL(wcvt_kernel, dim3(128), dim3(256), 0, stream,
                     qkv_w, proj_w, wq, wp);
  hipLaunchKernelGGL(swin_fused, dim3(NWIN), dim3(512), 0, stream,
                     x, q_bias, v_bias, logit_scale, biasC,
                     wq, wp, proj_b, out);
}